// Round 4
// baseline (514.771 us; speedup 1.0000x reference)
//
#include <hip/hip_runtime.h>

#define B_ 16
#define C_ 512
#define N_ 2048
#define D_ 64

typedef unsigned short u16;
typedef unsigned int   u32;
typedef __bf16 bfv4 __attribute__((ext_vector_type(4)));
typedef __bf16 bfv8 __attribute__((ext_vector_type(8)));
typedef float  f4   __attribute__((ext_vector_type(4)));
typedef float  f16v __attribute__((ext_vector_type(16)));

__device__ __forceinline__ u16 f2bf(float f) {          // RNE (cold paths)
  u32 u = __float_as_uint(f);
  return (u16)((u + 0x7FFFu + ((u >> 16) & 1u)) >> 16);
}
__device__ __forceinline__ u32 pack2(float a, float b) {  // RNE pair
  return (u32)f2bf(a) | ((u32)f2bf(b) << 16);
}
__device__ __forceinline__ u32 pack2t(float a, float b) { // truncation pair (hot)
  return (__float_as_uint(a) >> 16) | (__float_as_uint(b) & 0xFFFF0000u);
}
// 8-byte-aligned LDS load of 8 bf16 (2 x ds_read_b64)
__device__ __forceinline__ bfv8 ld8(const u16* p) {
  bfv4 lo = *(const bfv4*)p;
  bfv4 hi = *(const bfv4*)(p + 4);
  bfv8 r;
  r[0] = lo[0]; r[1] = lo[1]; r[2] = lo[2]; r[3] = lo[3];
  r[4] = hi[0]; r[5] = hi[1]; r[6] = hi[2]; r[7] = hi[3];
  return r;
}

// ---------------- all W -> bf16, one launch ----------------
__global__ __launch_bounds__(256) void conv_all(
    const float* __restrict__ Wq, const float* __restrict__ Wk,
    const float* __restrict__ Wv,
    u16* __restrict__ Wqb, u16* __restrict__ Wkb, u16* __restrict__ Wvb) {
  const int q4 = D_ * C_ / 4;   // 8192
  const int v4 = C_ * C_ / 4;   // 65536
  int i = blockIdx.x * 256 + threadIdx.x;
  const float* src; u16* dst; int j;
  if (i < q4)            { src = Wq; dst = Wqb; j = i; }
  else if (i < 2 * q4)   { src = Wk; dst = Wkb; j = i - q4; }
  else                   { j = i - 2 * q4; if (j >= v4) return; src = Wv; dst = Wvb; }
  float4 v = ((const float4*)src)[j];
  ((uint2*)dst)[j] = make_uint2(pack2(v.x, v.y), pack2(v.z, v.w));
}

// ---------------- fused transpose + Q/K/V projection, n-tile 32 ----------------
#define XS_STR 516   // u16 row stride (8B-aligned rows; 258 dw)
__global__ __launch_bounds__(256, 4) void proj_all(
    const float* __restrict__ x,
    const u16* __restrict__ Wqb, const u16* __restrict__ Wkb,
    const float* __restrict__ bq, const float* __restrict__ bk,
    const u16* __restrict__ Wvb, const float* __restrict__ bv,
    u16* __restrict__ Qb, u16* __restrict__ Kb, u16* __restrict__ Vb) {
  __shared__ u16 xs[32][XS_STR];    // [n][c] bf16
  const int b = blockIdx.x, n0 = blockIdx.y * 32;
  const int t = threadIdx.x;
  const int w = t >> 6, lane = t & 63;
  const int l15 = lane & 15, quad = lane >> 4;
  const int l31 = lane & 31, h = lane >> 5;

  // ---- stage + transpose: 8 passes; lanes: cp = t&31 (c-pairs), n4 = t>>5 ----
  {
    const int cp = t & 31, n4 = t >> 5;
#pragma unroll
    for (int p = 0; p < 8; p++) {
      int c = p * 64 + cp * 2;
      const size_t rb = ((size_t)(b * C_) + c) * N_ + n0 + n4 * 4;
      float4 a = *(const float4*)&x[rb];
      float4 bb = *(const float4*)&x[rb + N_];
      *(u32*)&xs[n4 * 4 + 0][c] = pack2t(a.x, bb.x);
      *(u32*)&xs[n4 * 4 + 1][c] = pack2t(a.y, bb.y);
      *(u32*)&xs[n4 * 4 + 2][c] = pack2t(a.z, bb.z);
      *(u32*)&xs[n4 * 4 + 3][c] = pack2t(a.w, bb.w);
    }
  }
  __syncthreads();

  // ---- Q/K: wave 0,1 -> Q (n-halves), wave 2,3 -> K ----
  {
    const u16* Wb = (w < 2) ? Wqb : Wkb;
    const float* bias = (w < 2) ? bq : bk;
    u16* Ob = (w < 2) ? Qb : Kb;
    const int nh = w & 1;
    f4 acc[4];
#pragma unroll
    for (int mt = 0; mt < 4; mt++) acc[mt] = (f4)(0.0f);
    const u16* xrow = &xs[nh * 16 + l15][0];
    for (int kc = 0; kc < 16; kc++) {
      bfv8 bx = ld8(&xrow[kc * 32 + quad * 8]);
#pragma unroll
      for (int mt = 0; mt < 4; mt++) {
        bfv8 a = *(const bfv8*)&Wb[(size_t)(mt * 16 + l15) * C_ + kc * 32 + quad * 8];
        acc[mt] = __builtin_amdgcn_mfma_f32_16x16x32_bf16(a, bx, acc[mt], 0, 0, 0);
      }
    }
    const size_t orow = ((size_t)(b * N_) + n0 + nh * 16 + l15) * D_;
#pragma unroll
    for (int mt = 0; mt < 4; mt++) {
      f4 b4 = *(const f4*)&bias[mt * 16 + quad * 4];
      *(uint2*)&Ob[orow + mt * 16 + quad * 4] =
          make_uint2(pack2(acc[mt][0] + b4[0], acc[mt][1] + b4[1]),
                     pack2(acc[mt][2] + b4[2], acc[mt][3] + b4[3]));
    }
  }

  // ---- V: wave w owns c-range w*128; n = l31 ----
  {
    f16v acc[4];
#pragma unroll
    for (int mt = 0; mt < 4; mt++) acc[mt] = (f16v)(0.0f);
    for (int kc = 0; kc < 32; kc++) {
      bfv8 bx = ld8(&xs[l31][kc * 16 + h * 8]);
#pragma unroll
      for (int mt = 0; mt < 4; mt++) {
        bfv8 a = *(const bfv8*)&Wvb[(size_t)(w * 128 + mt * 32 + l31) * C_ + kc * 16 + h * 8];
        acc[mt] = __builtin_amdgcn_mfma_f32_32x32x16_bf16(a, bx, acc[mt], 0, 0, 0);
      }
    }
#pragma unroll
    for (int mt = 0; mt < 4; mt++)
#pragma unroll
      for (int g = 0; g < 4; g++) {
        f4 bv4 = *(const f4*)&bv[w * 128 + mt * 32 + g * 8 + h * 4];
#pragma unroll
        for (int r = 0; r < 4; r++) {
          int c = w * 128 + mt * 32 + g * 8 + h * 4 + r;
          Vb[((size_t)(b * C_) + c) * N_ + n0 + l31] = f2bf(acc[mt][g * 4 + r] + bv4[r]);
        }
      }
  }
}

// ---------------- fused attention, i-tile 32, 4 blocks/CU ----------------
#define PS_STR 68   // u16 (8B-aligned rows; 34 dw -> 2-way on b64, free)
__global__ __launch_bounds__(256, 4) void attn(
    const float* __restrict__ x, const u16* __restrict__ Qb,
    const u16* __restrict__ Kb, const u16* __restrict__ Vb,
    const float* __restrict__ gamma, float* __restrict__ out) {
  __shared__ u16 Ps[2][32][PS_STR];
  __shared__ float pl[4][16];
  __shared__ float invl[32];
  const int b = blockIdx.x, i0 = blockIdx.y * 32;
  const int t = threadIdx.x, w = t >> 6, lane = t & 63;
  const int l15 = lane & 15, quad = lane >> 4;
  const int l31 = lane & 31, h = lane >> 5;
  const int ih = w & 1;        // i-half this wave computes in E
  const int jh = w >> 1;       // j-half this wave computes in E

  // Q B-frags for i-cols ih*16 + l15
  bfv8 qf[2];
#pragma unroll
  for (int kc = 0; kc < 2; kc++)
    qf[kc] = *(const bfv8*)&Qb[((size_t)(b * N_) + i0 + ih * 16 + l15) * D_ + kc * 32 + quad * 8];

  f16v acc[4];   // nt: c = w*128 + nt*32
#pragma unroll
  for (int nt = 0; nt < 4; nt++) acc[nt] = (f16v)(0.0f);
  float l_acc = 0.0f;

  const u16* Vbase = &Vb[((size_t)(b * C_) + w * 128) * N_];
  const u16* Kbase = &Kb[(size_t)(b * N_) * D_];

  int buf = 0;
  for (int j0 = 0; j0 < N_; j0 += 64, buf ^= 1) {
    // issue V kc=0 fragment loads NOW; they complete during E + barrier
    bfv8 vpre[4];
#pragma unroll
    for (int nt = 0; nt < 4; nt++)
      vpre[nt] = *(const bfv8*)&Vbase[(size_t)(nt * 32 + l31) * N_ + j0 + h * 8];

    // E^T: this wave covers j in [jh*32, jh*32+32), i-cols ih*16..+15
#pragma unroll
    for (int jt = 0; jt < 2; jt++) {
      f4 e = (f4)(0.0f);
#pragma unroll
      for (int kc = 0; kc < 2; kc++) {
        bfv8 kf = *(const bfv8*)&Kbase[(size_t)(j0 + jh * 32 + jt * 16 + l15) * D_ + kc * 32 + quad * 8];
        e = __builtin_amdgcn_mfma_f32_16x16x32_bf16(kf, qf[kc], e, 0, 0, 0);
      }
      float p0 = __expf(e[0]), p1 = __expf(e[1]);
      float p2 = __expf(e[2]), p3 = __expf(e[3]);
      l_acc += (p0 + p1) + (p2 + p3);
      *(uint2*)&Ps[buf][ih * 16 + l15][jh * 32 + jt * 16 + quad * 4] =
          make_uint2(pack2t(p0, p1), pack2t(p2, p3));
    }
    __syncthreads();
    // PV: A = P (LDS, m = i = l31), B = V (global)
#pragma unroll
    for (int kc = 0; kc < 4; kc++) {
      bfv8 pa = ld8(&Ps[buf][l31][kc * 16 + h * 8]);
      bfv8 vb[4];
      if (kc == 0) {
#pragma unroll
        for (int nt = 0; nt < 4; nt++) vb[nt] = vpre[nt];
      } else {
#pragma unroll
        for (int nt = 0; nt < 4; nt++)
          vb[nt] = *(const bfv8*)&Vbase[(size_t)(nt * 32 + l31) * N_ + j0 + kc * 16 + h * 8];
      }
#pragma unroll
      for (int nt = 0; nt < 4; nt++)
        acc[nt] = __builtin_amdgcn_mfma_f32_32x32x16_bf16(pa, vb[nt], acc[nt], 0, 0, 0);
    }
  }

  // row-sum l: reduce quads in-wave, then cross-wave halves via LDS
  float lt = l_acc;
  lt += __shfl_xor(lt, 16, 64);
  lt += __shfl_xor(lt, 32, 64);
  if (lane < 16) pl[w][l15] = lt;
  __syncthreads();
  if (t < 32) invl[t] = 1.0f / (pl[t >> 4][t & 15] + pl[(t >> 4) + 2][t & 15]);
  __syncthreads();

  const float gam = gamma[0];
#pragma unroll
  for (int nt = 0; nt < 4; nt++) {
    int c = w * 128 + nt * 32 + l31;
#pragma unroll
    for (int g = 0; g < 4; g++) {
      int ib = g * 8 + h * 4;           // rows i = ib + r
      f4 il = *(const f4*)&invl[ib];
      size_t off = ((size_t)(b * C_) + c) * N_ + i0 + ib;
      f4 xv = *(const f4*)&x[off];
      f4 o;
#pragma unroll
      for (int r = 0; r < 4; r++)
        o[r] = xv[r] + gam * acc[nt][g * 4 + r] * il[r];
      *(f4*)&out[off] = o;
    }
  }
}

extern "C" void kernel_launch(void* const* d_in, const int* in_sizes, int n_in,
                              void* d_out, int out_size, void* d_ws, size_t ws_size,
                              hipStream_t stream) {
  const float* x     = (const float*)d_in[0];
  const float* Wq    = (const float*)d_in[1];
  const float* bq    = (const float*)d_in[2];
  const float* Wk    = (const float*)d_in[3];
  const float* bk    = (const float*)d_in[4];
  const float* Wv    = (const float*)d_in[5];
  const float* bv    = (const float*)d_in[6];
  const float* gamma = (const float*)d_in[7];
  float* out = (float*)d_out;

  u16* wsu = (u16*)d_ws;
  u16* Qb  = wsu;                                   // B*N*D
  u16* Kb  = Qb  + (size_t)B_ * N_ * D_;            // B*N*D
  u16* Vb  = Kb  + (size_t)B_ * N_ * D_;            // B*C*N
  u16* Wqb = Vb  + (size_t)B_ * C_ * N_;            // D*C
  u16* Wkb = Wqb + (size_t)D_ * C_;                 // D*C
  u16* Wvb = Wkb + (size_t)D_ * C_;                 // C*C

  conv_all<<<dim3(320), 256, 0, stream>>>(Wq, Wk, Wv, Wqb, Wkb, Wvb);
  proj_all<<<dim3(B_, N_ / 32), 256, 0, stream>>>(x, Wqb, Wkb, bq, bk, Wvb, bv, Qb, Kb, Vb);
  attn<<<dim3(B_, N_ / 32), 256, 0, stream>>>(x, Qb, Kb, Vb, gamma, out);
}

// Round 5
// 375.819 us; speedup vs baseline: 1.3697x; 1.3697x over previous
//
#include <hip/hip_runtime.h>

#define B_ 16
#define C_ 512
#define N_ 2048
#define D_ 64

typedef unsigned short u16;
typedef unsigned int   u32;
typedef __bf16 bfv4 __attribute__((ext_vector_type(4)));
typedef __bf16 bfv8 __attribute__((ext_vector_type(8)));
typedef float  f4   __attribute__((ext_vector_type(4)));
typedef float  f16v __attribute__((ext_vector_type(16)));

__device__ __forceinline__ u16 f2bf(float f) {          // RNE (cold paths)
  u32 u = __float_as_uint(f);
  return (u16)((u + 0x7FFFu + ((u >> 16) & 1u)) >> 16);
}
__device__ __forceinline__ u32 pack2(float a, float b) {  // RNE pair
  return (u32)f2bf(a) | ((u32)f2bf(b) << 16);
}
__device__ __forceinline__ u32 pack2t(float a, float b) { // truncation pair (hot)
  return (__float_as_uint(a) >> 16) | (__float_as_uint(b) & 0xFFFF0000u);
}
// 8-byte-aligned LDS load of 8 bf16 (2 x ds_read_b64)
__device__ __forceinline__ bfv8 ld8(const u16* p) {
  bfv4 lo = *(const bfv4*)p;
  bfv4 hi = *(const bfv4*)(p + 4);
  bfv8 r;
  r[0] = lo[0]; r[1] = lo[1]; r[2] = lo[2]; r[3] = lo[3];
  r[4] = hi[0]; r[5] = hi[1]; r[6] = hi[2]; r[7] = hi[3];
  return r;
}

// ---------------- all W -> bf16, one launch ----------------
__global__ __launch_bounds__(256) void conv_all(
    const float* __restrict__ Wq, const float* __restrict__ Wk,
    const float* __restrict__ Wv,
    u16* __restrict__ Wqb, u16* __restrict__ Wkb, u16* __restrict__ Wvb) {
  const int q4 = D_ * C_ / 4;   // 8192
  const int v4 = C_ * C_ / 4;   // 65536
  int i = blockIdx.x * 256 + threadIdx.x;
  const float* src; u16* dst; int j;
  if (i < q4)            { src = Wq; dst = Wqb; j = i; }
  else if (i < 2 * q4)   { src = Wk; dst = Wkb; j = i - q4; }
  else                   { j = i - 2 * q4; if (j >= v4) return; src = Wv; dst = Wvb; }
  float4 v = ((const float4*)src)[j];
  ((uint2*)dst)[j] = make_uint2(pack2(v.x, v.y), pack2(v.z, v.w));
}

// ---------------- fused transpose + Q/K/V projection (R3 shape) ----------------
#define XS_STR 516   // u16 row stride: 258 dwords -> 2-way bank pattern (free)
__global__ __launch_bounds__(256, 2) void proj_all(
    const float* __restrict__ x,
    const u16* __restrict__ Wqb, const u16* __restrict__ Wkb,
    const float* __restrict__ bq, const float* __restrict__ bk,
    const u16* __restrict__ Wvb, const float* __restrict__ bv,
    u16* __restrict__ Qb, u16* __restrict__ Kb, u16* __restrict__ Vb) {
  __shared__ u16 xs[64][XS_STR];    // [n][c]
  const int b = blockIdx.x, n0 = blockIdx.y * 64;
  const int t = threadIdx.x;
  const int w = t >> 6, lane = t & 63;
  const int l15 = lane & 15, quad = lane >> 4;
  const int l31 = lane & 31, h = lane >> 5;

  // ---- stage + transpose ----
  {
    const int n4 = t & 15, cp = t >> 4;
    for (int p = 0; p < 16; p++) {
      int c = p * 32 + cp * 2;
      const size_t rb = ((size_t)(b * C_) + c) * N_ + n0 + n4 * 4;
      float4 a = *(const float4*)&x[rb];
      float4 bb = *(const float4*)&x[rb + N_];
      *(u32*)&xs[n4 * 4 + 0][c] = pack2t(a.x, bb.x);
      *(u32*)&xs[n4 * 4 + 1][c] = pack2t(a.y, bb.y);
      *(u32*)&xs[n4 * 4 + 2][c] = pack2t(a.z, bb.z);
      *(u32*)&xs[n4 * 4 + 3][c] = pack2t(a.w, bb.w);
    }
  }
  __syncthreads();

  // ---- Q/K: wave w owns n-subtile w*16 ----
  {
    f4 accQ[4], accK[4];
#pragma unroll
    for (int mt = 0; mt < 4; mt++) { accQ[mt] = (f4)(0.0f); accK[mt] = (f4)(0.0f); }
    const u16* xrow = &xs[w * 16 + l15][0];
    for (int kc = 0; kc < 16; kc++) {
      bfv8 bx = ld8(&xrow[kc * 32 + quad * 8]);
#pragma unroll
      for (int mt = 0; mt < 4; mt++) {
        bfv8 aq = *(const bfv8*)&Wqb[(size_t)(mt * 16 + l15) * C_ + kc * 32 + quad * 8];
        bfv8 ak = *(const bfv8*)&Wkb[(size_t)(mt * 16 + l15) * C_ + kc * 32 + quad * 8];
        accQ[mt] = __builtin_amdgcn_mfma_f32_16x16x32_bf16(aq, bx, accQ[mt], 0, 0, 0);
        accK[mt] = __builtin_amdgcn_mfma_f32_16x16x32_bf16(ak, bx, accK[mt], 0, 0, 0);
      }
    }
    const size_t orow = ((size_t)(b * N_) + n0 + w * 16 + l15) * D_;
#pragma unroll
    for (int mt = 0; mt < 4; mt++) {
      f4 bq4 = *(const f4*)&bq[mt * 16 + quad * 4];
      f4 bk4 = *(const f4*)&bk[mt * 16 + quad * 4];
      *(uint2*)&Qb[orow + mt * 16 + quad * 4] =
          make_uint2(pack2(accQ[mt][0] + bq4[0], accQ[mt][1] + bq4[1]),
                     pack2(accQ[mt][2] + bq4[2], accQ[mt][3] + bq4[3]));
      *(uint2*)&Kb[orow + mt * 16 + quad * 4] =
          make_uint2(pack2(accK[mt][0] + bk4[0], accK[mt][1] + bk4[1]),
                     pack2(accK[mt][2] + bk4[2], accK[mt][3] + bk4[3]));
    }
  }

  // ---- V: wave w owns c-range w*128, 4 mt x 2 nt of 32x32x16 ----
  {
    f16v acc[4][2];
#pragma unroll
    for (int mt = 0; mt < 4; mt++)
#pragma unroll
      for (int nt = 0; nt < 2; nt++) acc[mt][nt] = (f16v)(0.0f);
    for (int kc = 0; kc < 32; kc++) {
      bfv8 bx[2];
#pragma unroll
      for (int nt = 0; nt < 2; nt++)
        bx[nt] = ld8(&xs[nt * 32 + l31][kc * 16 + h * 8]);
#pragma unroll
      for (int mt = 0; mt < 4; mt++) {
        bfv8 a = *(const bfv8*)&Wvb[(size_t)(w * 128 + mt * 32 + l31) * C_ + kc * 16 + h * 8];
#pragma unroll
        for (int nt = 0; nt < 2; nt++)
          acc[mt][nt] = __builtin_amdgcn_mfma_f32_32x32x16_bf16(a, bx[nt], acc[mt][nt], 0, 0, 0);
      }
    }
#pragma unroll
    for (int mt = 0; mt < 4; mt++)
#pragma unroll
      for (int nt = 0; nt < 2; nt++)
#pragma unroll
        for (int g = 0; g < 4; g++) {
          f4 bv4 = *(const f4*)&bv[w * 128 + mt * 32 + g * 8 + h * 4];
#pragma unroll
          for (int r = 0; r < 4; r++) {
            int c = w * 128 + mt * 32 + g * 8 + h * 4 + r;
            Vb[((size_t)(b * C_) + c) * N_ + n0 + nt * 32 + l31] =
                f2bf(acc[mt][nt][g * 4 + r] + bv4[r]);
          }
        }
  }
}

// ---------------- fused attention: i-tile 64, j-tile 128 ----------------
#define PS_STR 140  // u16: 70 dw -> 6*l mod 32 pattern = 2-way on b64 (free); 8B-aligned
__global__ __launch_bounds__(256, 2) void attn(
    const float* __restrict__ x, const u16* __restrict__ Qb,
    const u16* __restrict__ Kb, const u16* __restrict__ Vb,
    const float* __restrict__ gamma, float* __restrict__ out) {
  __shared__ u16 Ps[2][64][PS_STR];
  __shared__ float invl[64];
  const int b = blockIdx.x, i0 = blockIdx.y * 64;
  const int t = threadIdx.x, w = t >> 6, lane = t & 63;
  const int l15 = lane & 15, quad = lane >> 4;
  const int l31 = lane & 31, h = lane >> 5;

  bfv8 qf[2];
#pragma unroll
  for (int kc = 0; kc < 2; kc++)
    qf[kc] = *(const bfv8*)&Qb[((size_t)(b * N_) + i0 + w * 16 + l15) * D_ + kc * 32 + quad * 8];

  f16v acc[2][4];   // mt: i 0..63, nt: c = w*128 + nt*32
#pragma unroll
  for (int mt = 0; mt < 2; mt++)
#pragma unroll
    for (int nt = 0; nt < 4; nt++) acc[mt][nt] = (f16v)(0.0f);
  float l_acc = 0.0f;

  const u16* Vbase = &Vb[((size_t)(b * C_) + w * 128) * N_];
  const u16* Kbase = &Kb[(size_t)(b * N_) * D_];

  int buf = 0;
  for (int j0 = 0; j0 < N_; j0 += 128, buf ^= 1) {
    // V kc=0 fragment loads issued first; complete during E + barrier
    bfv8 vpre[4];
#pragma unroll
    for (int nt = 0; nt < 4; nt++)
      vpre[nt] = *(const bfv8*)&Vbase[(size_t)(nt * 32 + l31) * N_ + j0 + h * 8];

    // E^T: wave w covers cols i = w*16..+15, all 128 j
#pragma unroll
    for (int jt = 0; jt < 8; jt++) {
      f4 e = (f4)(0.0f);
#pragma unroll
      for (int kc = 0; kc < 2; kc++) {
        bfv8 kf = *(const bfv8*)&Kbase[(size_t)(j0 + jt * 16 + l15) * D_ + kc * 32 + quad * 8];
        e = __builtin_amdgcn_mfma_f32_16x16x32_bf16(kf, qf[kc], e, 0, 0, 0);
      }
      float p0 = __expf(e[0]), p1 = __expf(e[1]);
      float p2 = __expf(e[2]), p3 = __expf(e[3]);
      l_acc += (p0 + p1) + (p2 + p3);
      *(uint2*)&Ps[buf][w * 16 + l15][jt * 16 + quad * 4] =
          make_uint2(pack2t(p0, p1), pack2t(p2, p3));
    }
    __syncthreads();
    // PV: A = P (LDS), B = V (global), 8 kc x (2 mt x 4 nt)
#pragma unroll
    for (int kc = 0; kc < 8; kc++) {
      bfv8 pa[2];
#pragma unroll
      for (int mt = 0; mt < 2; mt++)
        pa[mt] = ld8(&Ps[buf][mt * 32 + l31][kc * 16 + h * 8]);
      bfv8 vb[4];
      if (kc == 0) {
#pragma unroll
        for (int nt = 0; nt < 4; nt++) vb[nt] = vpre[nt];
      } else {
#pragma unroll
        for (int nt = 0; nt < 4; nt++)
          vb[nt] = *(const bfv8*)&Vbase[(size_t)(nt * 32 + l31) * N_ + j0 + kc * 16 + h * 8];
      }
#pragma unroll
      for (int mt = 0; mt < 2; mt++)
#pragma unroll
        for (int nt = 0; nt < 4; nt++)
          acc[mt][nt] = __builtin_amdgcn_mfma_f32_32x32x16_bf16(pa[mt], vb[nt], acc[mt][nt], 0, 0, 0);
    }
  }

  // l: wave w owns i = w*16 + l15; reduce over quads only
  float lt = l_acc;
  lt += __shfl_xor(lt, 16, 64);
  lt += __shfl_xor(lt, 32, 64);
  if (lane < 16) invl[w * 16 + l15] = 1.0f / lt;
  __syncthreads();

  const float gam = gamma[0];
#pragma unroll
  for (int mt = 0; mt < 2; mt++)
#pragma unroll
    for (int nt = 0; nt < 4; nt++) {
      int c = w * 128 + nt * 32 + l31;
#pragma unroll
      for (int g = 0; g < 4; g++) {
        int ib = mt * 32 + g * 8 + h * 4;
        f4 il = *(const f4*)&invl[ib];
        size_t off = ((size_t)(b * C_) + c) * N_ + i0 + ib;
        f4 xv = *(const f4*)&x[off];
        f4 o;
#pragma unroll
        for (int r = 0; r < 4; r++)
          o[r] = xv[r] + gam * acc[mt][nt][g * 4 + r] * il[r];
        *(f4*)&out[off] = o;
      }
    }
}

extern "C" void kernel_launch(void* const* d_in, const int* in_sizes, int n_in,
                              void* d_out, int out_size, void* d_ws, size_t ws_size,
                              hipStream_t stream) {
  const float* x     = (const float*)d_in[0];
  const float* Wq    = (const float*)d_in[1];
  const float* bq    = (const float*)d_in[2];
  const float* Wk    = (const float*)d_in[3];
  const float* bk    = (const float*)d_in[4];
  const float* Wv    = (const float*)d_in[5];
  const float* bv    = (const float*)d_in[6];
  const float* gamma = (const float*)d_in[7];
  float* out = (float*)d_out;

  u16* wsu = (u16*)d_ws;
  u16* Qb  = wsu;                                   // B*N*D
  u16* Kb  = Qb  + (size_t)B_ * N_ * D_;            // B*N*D
  u16* Vb  = Kb  + (size_t)B_ * N_ * D_;            // B*C*N
  u16* Wqb = Vb  + (size_t)B_ * C_ * N_;            // D*C
  u16* Wkb = Wqb + (size_t)D_ * C_;                 // D*C
  u16* Wvb = Wkb + (size_t)D_ * C_;                 // C*C

  conv_all<<<dim3(320), 256, 0, stream>>>(Wq, Wk, Wv, Wqb, Wkb, Wvb);
  proj_all<<<dim3(B_, N_ / 64), 256, 0, stream>>>(x, Wqb, Wkb, bq, bk, Wvb, bv, Qb, Kb, Vb);
  attn<<<dim3(B_, N_ / 64), 256, 0, stream>>>(x, Qb, Kb, Vb, gamma, out);
}